// Round 7
// baseline (394.567 us; speedup 1.0000x reference)
//
#include <hip/hip_runtime.h>

#define TOK 64
#define CDIM 192
#define NH 6
#define HD 32
#define THREADS 768
#define QSCALE 0.17677669529663687f  // 32^-0.5

// workspace layout (halfs): w_qkv16 [576*192] | w_proj16 [192*192] | bias frags [6*4*64*16]
#define WQ16_OFF 0
#define WP16_OFF 110592
#define BIAS_OFF 147456
#define WS_HALFS (147456 + 24576)
#define WS_BYTES (WS_HALFS * 2)

typedef _Float16 f16x8 __attribute__((ext_vector_type(8)));
typedef _Float16 f16x4 __attribute__((ext_vector_type(4)));
typedef float f32x4 __attribute__((ext_vector_type(4)));

__device__ __forceinline__ f16x8 ld8(const _Float16* p) {
  return *reinterpret_cast<const f16x8*>(p);
}

__device__ __forceinline__ f16x8 cvt8(const float* __restrict__ p) {
  float4 a = *reinterpret_cast<const float4*>(p);
  float4 c = *reinterpret_cast<const float4*>(p + 4);
  f16x8 r;
  r[0] = (_Float16)a.x; r[1] = (_Float16)a.y; r[2] = (_Float16)a.z; r[3] = (_Float16)a.w;
  r[4] = (_Float16)c.x; r[5] = (_Float16)c.y; r[6] = (_Float16)c.z; r[7] = (_Float16)c.w;
  return r;
}

// Prologue: fp16 weights + per-(head,row-tile) bias fragments (two f16x8 per lane).
__global__ void prep_ws(const float* __restrict__ wq, const float* __restrict__ wp,
                        const float* __restrict__ bt, _Float16* __restrict__ ws) {
  int i = blockIdx.x * 256 + threadIdx.x;
  if (i < 27648) {
    float4 v = reinterpret_cast<const float4*>(wq)[i];
    f16x4 h;
    h[0] = (_Float16)v.x; h[1] = (_Float16)v.y; h[2] = (_Float16)v.z; h[3] = (_Float16)v.w;
    *reinterpret_cast<f16x4*>(ws + WQ16_OFF + (size_t)i * 4) = h;
  } else if (i < 36864) {
    int j = i - 27648;
    float4 v = reinterpret_cast<const float4*>(wp)[j];
    f16x4 h;
    h[0] = (_Float16)v.x; h[1] = (_Float16)v.y; h[2] = (_Float16)v.z; h[3] = (_Float16)v.w;
    *reinterpret_cast<f16x4*>(ws + WP16_OFF + (size_t)j * 4) = h;
  } else if (i < 61440) {
    int j = i - 36864;            // ((h*4+it)*64 + lane)*16 + (jt*4+r)
    int hit = j >> 10;
    int l = (j >> 4) & 63;
    int s = j & 15;
    int h = hit >> 2, it = hit & 3;
    int ii = it * 16 + (l & 15);
    int jj = (s >> 2) * 16 + (l >> 4) * 4 + (s & 3);
    int rel = ((ii >> 3) - (jj >> 3) + 7) * 15 + ((ii & 7) - (jj & 7) + 7);
    ws[BIAS_OFF + j] = (_Float16)bt[rel * NH + h];
  }
}

// Fused window attention: 1 block = 1 window, 12 waves, 48 KB LDS -> 2 blocks/CU.
// QKV in two passes (q+k, then v) to stay under the 85-reg budget (round 6).
// NEW (round 7): XOR token-swizzle per panel (slot = token ^ (panel&7)) kills
// the x-staging bank conflicts (1 KB panels are bank-aligned, so same-token
// slots across panels alias). All fragment reads remain ds_read_b128,
// lane-permuted but conflict-free. Staging is 32 B/lane, globally coalesced.
// Overlay chains: R1: x -> v^T -> O      R2: k -> q -> P slices
template <bool WS>
__global__ __launch_bounds__(THREADS, 6) void winattn(
    const float* __restrict__ x, const float* __restrict__ w_qkv,
    const float* __restrict__ b_qkv, const float* __restrict__ w_proj,
    const float* __restrict__ b_proj, const float* __restrict__ bias_table,
    const _Float16* __restrict__ ws, float* __restrict__ out) {
  __shared__ __align__(16) _Float16 R1[12288];  // x -> v^T -> O
  __shared__ __align__(16) _Float16 R2[12288];  // k -> q -> P

  const int tid = threadIdx.x;
  const int w   = tid >> 6;   // 0..11
  const int l   = tid & 63;
  const int l15 = l & 15;
  const int lg  = l >> 4;
  const int b   = blockIdx.x;
  const int h   = w >> 1;     // head
  const int wh  = w & 1;      // half (dims in QKV, rows in attention)
  const f32x4 vzero = {0.f, 0.f, 0.f, 0.f};

  // ---------------- stage x (fp32 -> fp16 swizzled panels) ----------------
  // chunk q = 8 floats; global float offset q*8 = 32B * tid -> fully coalesced.
  const float* xg = x + (size_t)b * (TOK * CDIM);
#pragma unroll
  for (int kk = 0; kk < 2; ++kk) {
    int q = tid + kk * 768;
    int n = q / 24;              // token
    int p = q - n * 24;          // c-panel
    const float* src = xg + q * 8;
    float4 v0 = *reinterpret_cast<const float4*>(src);
    float4 v1 = *reinterpret_cast<const float4*>(src + 4);
    f16x8 h8;
    h8[0] = (_Float16)v0.x; h8[1] = (_Float16)v0.y;
    h8[2] = (_Float16)v0.z; h8[3] = (_Float16)v0.w;
    h8[4] = (_Float16)v1.x; h8[5] = (_Float16)v1.y;
    h8[6] = (_Float16)v1.z; h8[7] = (_Float16)v1.w;
    *reinterpret_cast<f16x8*>(&R1[(p * TOK + (n ^ (p & 7))) * 8]) = h8;
  }
  __syncthreads();  // b0

  const int sdl = h * HD + wh * 16 + l15;  // out-dim within each part
  const int hd  = wh * 16 + l15;           // dim within head
  const int dp  = hd >> 3;                 // d-panel (0..3) for k/q regions

  // ------- QKV pass A: q + k (K=192) -------
  f32x4 aq[4], ak[4];
#pragma unroll
  for (int mt = 0; mt < 4; ++mt) { aq[mt] = vzero; ak[mt] = vzero; }
#pragma unroll
  for (int ks = 0; ks < 6; ++ks) {
    const int sp = (ks * 4) & 7;  // panel-swizzle base; panel = ks*4+lg
    f16x8 a[4];
#pragma unroll
    for (int mt = 0; mt < 4; ++mt)
      a[mt] = ld8(&R1[((ks * 4 + lg) * TOK + ((mt * 16 + l15) ^ (sp + lg))) * 8]);
    f16x8 bfq, bfk;
    if constexpr (WS) {
      bfq = ld8(ws + WQ16_OFF + (size_t)sdl * CDIM + ks * 32 + lg * 8);
      bfk = ld8(ws + WQ16_OFF + (size_t)(CDIM + sdl) * CDIM + ks * 32 + lg * 8);
    } else {
      bfq = cvt8(w_qkv + (size_t)sdl * CDIM + ks * 32 + lg * 8);
      bfk = cvt8(w_qkv + (size_t)(CDIM + sdl) * CDIM + ks * 32 + lg * 8);
    }
    __builtin_amdgcn_s_setprio(1);
#pragma unroll
    for (int mt = 0; mt < 4; ++mt) {
      aq[mt] = __builtin_amdgcn_mfma_f32_16x16x32_f16(a[mt], bfq, aq[mt], 0, 0, 0);
      ak[mt] = __builtin_amdgcn_mfma_f32_16x16x32_f16(a[mt], bfk, ak[mt], 0, 0, 0);
    }
    __builtin_amdgcn_s_setprio(0);
  }
  // k -> R2 (ak dies); slot = token ^ dp
  {
    float bq1 = b_qkv[CDIM + sdl];
#pragma unroll
    for (int mt = 0; mt < 4; ++mt)
#pragma unroll
      for (int r = 0; r < 4; ++r) {
        int n = mt * 16 + lg * 4 + r;
        R2[h * 2048 + (dp * TOK + (n ^ dp)) * 8 + (hd & 7)] = (_Float16)(ak[mt][r] + bq1);
      }
  }

  // ------- QKV pass B: v (x panels still resident) -------
  f32x4 av[4];
#pragma unroll
  for (int mt = 0; mt < 4; ++mt) av[mt] = vzero;
#pragma unroll
  for (int ks = 0; ks < 6; ++ks) {
    const int sp = (ks * 4) & 7;
    f16x8 a[4];
#pragma unroll
    for (int mt = 0; mt < 4; ++mt)
      a[mt] = ld8(&R1[((ks * 4 + lg) * TOK + ((mt * 16 + l15) ^ (sp + lg))) * 8]);
    f16x8 bfv;
    if constexpr (WS) bfv = ld8(ws + WQ16_OFF + (size_t)(2 * CDIM + sdl) * CDIM + ks * 32 + lg * 8);
    else              bfv = cvt8(w_qkv + (size_t)(2 * CDIM + sdl) * CDIM + ks * 32 + lg * 8);
    __builtin_amdgcn_s_setprio(1);
#pragma unroll
    for (int mt = 0; mt < 4; ++mt)
      av[mt] = __builtin_amdgcn_mfma_f32_16x16x32_f16(a[mt], bfv, av[mt], 0, 0, 0);
    __builtin_amdgcn_s_setprio(0);
  }
  __syncthreads();  // b1: x reads done (R1 free), k visible

  // hoist kf (swizzled read); v^T -> R1 over x, packed f16x4 (av dies)
  f16x8 kf[4];
#pragma unroll
  for (int jt = 0; jt < 4; ++jt)
    kf[jt] = ld8(&R2[h * 2048 + (lg * TOK + ((jt * 16 + l15) ^ lg)) * 8]);
  {
    float bq2 = b_qkv[2 * CDIM + sdl];
#pragma unroll
    for (int mt = 0; mt < 4; ++mt) {
      int vp = 2 * mt + (lg >> 1);          // token-panel (0..7)
      f16x4 pk;
#pragma unroll
      for (int r = 0; r < 4; ++r) pk[r] = (_Float16)(av[mt][r] + bq2);
      *reinterpret_cast<f16x4*>(
          &R1[h * 2048 + (vp * HD + (hd ^ vp)) * 8 + (lg & 1) * 4]) = pk;
    }
  }
  __syncthreads();  // b2: v^T visible, k dead (R2 region free)

  // hoist vf; q -> R2 over k (aq dies)
  f16x8 vf[4];
#pragma unroll
  for (int z = 0; z < 4; ++z) {  // z = ks*2+nt; token-panel tp = ks*4+lg
    int ks = z >> 1, nt = z & 1;
    int tp = ks * 4 + lg;
    vf[z] = ld8(&R1[h * 2048 + (tp * HD + ((nt * 16 + l15) ^ tp)) * 8]);
  }
  {
    float bq0 = b_qkv[sdl];
#pragma unroll
    for (int mt = 0; mt < 4; ++mt)
#pragma unroll
      for (int r = 0; r < 4; ++r) {
        int n = mt * 16 + lg * 4 + r;
        R2[h * 2048 + (dp * TOK + (n ^ dp)) * 8 + (hd & 7)] =
            (_Float16)((aq[mt][r] + bq0) * QSCALE);
      }
  }
  __syncthreads();  // b3: q visible, v^T dead (R1 free for O)

  // hoist qf (swizzled)
  f16x8 qf[2];
#pragma unroll
  for (int ii = 0; ii < 2; ++ii) {
    int it = wh * 2 + ii;
    qf[ii] = ld8(&R2[h * 2048 + (lg * TOK + ((it * 16 + l15) ^ lg)) * 8]);
  }
  __syncthreads();  // b4: q dead -> R2 free for P slices

  // ---------------- attention: 2 row-tiles per wave ----------------
  {
    _Float16* pbase = &R2[w * 1024];  // 2 KB P slice per wave (conflict-free layout)
#pragma unroll
    for (int ii = 0; ii < 2; ++ii) {
      const int it = wh * 2 + ii;
      f32x4 st[4];
      __builtin_amdgcn_s_setprio(1);
#pragma unroll
      for (int jt = 0; jt < 4; ++jt)
        st[jt] = __builtin_amdgcn_mfma_f32_16x16x32_f16(kf[jt], qf[ii], vzero, 0, 0, 0);
      __builtin_amdgcn_s_setprio(0);
      // bias: lane holds (i = it*16+l15, j = jt*16+lg*4+r)
      if constexpr (WS) {
        const _Float16* bw = ws + BIAS_OFF + ((h * 4 + it) * 64 + l) * 16;
        f16x8 b0 = ld8(bw), b1 = ld8(bw + 8);
#pragma unroll
        for (int jt = 0; jt < 4; ++jt)
#pragma unroll
          for (int r = 0; r < 4; ++r)
            st[jt][r] += (float)((jt < 2) ? b0[jt * 4 + r] : b1[(jt - 2) * 4 + r]);
      } else {
        int i = it * 16 + l15, yi = i >> 3, xi = i & 7;
#pragma unroll
        for (int jt = 0; jt < 4; ++jt)
#pragma unroll
          for (int r = 0; r < 4; ++r) {
            int j = jt * 16 + lg * 4 + r, yj = j >> 3, xj = j & 7;
            st[jt][r] += bias_table[(((yi - yj + 7) * 15 + (xi - xj + 7)) * NH + h)];
          }
      }
      // softmax over row i: 16 in-lane + lanes differing in lg (xor 16,32)
      float m = st[0][0];
#pragma unroll
      for (int jt = 0; jt < 4; ++jt)
#pragma unroll
        for (int r = 0; r < 4; ++r) m = fmaxf(m, st[jt][r]);
      m = fmaxf(m, __shfl_xor(m, 16, 64));
      m = fmaxf(m, __shfl_xor(m, 32, 64));
      float sum = 0.f;
#pragma unroll
      for (int jt = 0; jt < 4; ++jt)
#pragma unroll
        for (int r = 0; r < 4; ++r) { st[jt][r] = __expf(st[jt][r] - m); sum += st[jt][r]; }
      sum += __shfl_xor(sum, 16, 64);
      sum += __shfl_xor(sum, 32, 64);
      float inv = 1.f / sum;
      // P slice write (packed f16x4), layout [j>>3][i16][j&7]
#pragma unroll
      for (int jt = 0; jt < 4; ++jt) {
        f16x4 pk;
#pragma unroll
        for (int r = 0; r < 4; ++r) pk[r] = (_Float16)(st[jt][r] * inv);
        *reinterpret_cast<f16x4*>(
            &pbase[((jt * 2 + (lg >> 1)) * 16 + l15) * 8 + (lg & 1) * 4]) = pk;
      }
      // PV: O[16x32] = P[16x64] @ V[64x32]
      f32x4 o[2] = {vzero, vzero};
#pragma unroll
      for (int ks = 0; ks < 2; ++ks) {
        f16x8 pf = ld8(&pbase[((ks * 4 + lg) * 16 + l15) * 8]);
        __builtin_amdgcn_s_setprio(1);
#pragma unroll
        for (int nt = 0; nt < 2; ++nt)
          o[nt] = __builtin_amdgcn_mfma_f32_16x16x32_f16(pf, vf[ks * 2 + nt], o[nt], 0, 0, 0);
        __builtin_amdgcn_s_setprio(0);
      }
      // O -> R1 swizzled flat panels
#pragma unroll
      for (int nt = 0; nt < 2; ++nt) {
        int c = h * HD + nt * 16 + l15;
        int op = c >> 3;
#pragma unroll
        for (int r = 0; r < 4; ++r) {
          int i2 = it * 16 + lg * 4 + r;
          R1[(op * TOK + (i2 ^ (op & 7))) * 8 + (c & 7)] = (_Float16)o[nt][r];
        }
      }
    }
  }
  __syncthreads();  // b5: O visible

  // ------- projection (64x192, K=192); wave w -> e-tile w -------
  {
    const int e = w * 16 + l15;
    f32x4 pacc[4];
#pragma unroll
    for (int mt = 0; mt < 4; ++mt) pacc[mt] = vzero;
#pragma unroll
    for (int ks = 0; ks < 6; ++ks) {
      const int sp = (ks * 4) & 7;
      f16x8 bf;
      if constexpr (WS) bf = ld8(ws + WP16_OFF + (size_t)e * CDIM + ks * 32 + lg * 8);
      else              bf = cvt8(w_proj + (size_t)e * CDIM + ks * 32 + lg * 8);
      f16x8 a[4];
#pragma unroll
      for (int mt = 0; mt < 4; ++mt)
        a[mt] = ld8(&R1[((ks * 4 + lg) * TOK + ((mt * 16 + l15) ^ (sp + lg))) * 8]);
      __builtin_amdgcn_s_setprio(1);
#pragma unroll
      for (int mt = 0; mt < 4; ++mt)
        pacc[mt] = __builtin_amdgcn_mfma_f32_16x16x32_f16(a[mt], bf, pacc[mt], 0, 0, 0);
      __builtin_amdgcn_s_setprio(0);
    }
    float bp = b_proj[e];
#pragma unroll
    for (int mt = 0; mt < 4; ++mt)
#pragma unroll
      for (int r = 0; r < 4; ++r) {
        int n = mt * 16 + lg * 4 + r;
        out[((size_t)b * TOK + n) * CDIM + e] = pacc[mt][r] + bp;
      }
  }
}

extern "C" void kernel_launch(void* const* d_in, const int* in_sizes, int n_in,
                              void* d_out, int out_size, void* d_ws, size_t ws_size,
                              hipStream_t stream) {
  const float* x          = (const float*)d_in[0];
  const float* w_qkv      = (const float*)d_in[1];
  const float* b_qkv      = (const float*)d_in[2];
  const float* w_proj     = (const float*)d_in[3];
  const float* b_proj     = (const float*)d_in[4];
  const float* bias_table = (const float*)d_in[5];
  float* out = (float*)d_out;
  int B = in_sizes[0] / (TOK * CDIM);

  if (ws_size >= (size_t)WS_BYTES) {
    _Float16* ws = (_Float16*)d_ws;
    hipLaunchKernelGGL(prep_ws, dim3(240), dim3(256), 0, stream,
                       w_qkv, w_proj, bias_table, ws);
    hipLaunchKernelGGL(winattn<true>, dim3(B), dim3(THREADS), 0, stream,
                       x, w_qkv, b_qkv, w_proj, b_proj, bias_table, ws, out);
  } else {
    hipLaunchKernelGGL(winattn<false>, dim3(B), dim3(THREADS), 0, stream,
                       x, w_qkv, b_qkv, w_proj, b_proj, bias_table,
                       (const _Float16*)nullptr, out);
  }
}

// Round 8
// 385.477 us; speedup vs baseline: 1.0236x; 1.0236x over previous
//
#include <hip/hip_runtime.h>

#define TOK 64
#define CDIM 192
#define NH 6
#define HD 32
#define THREADS 768
#define QSCALE 0.17677669529663687f  // 32^-0.5

// workspace layout (halfs): w_qkv16 [576*192] | w_proj16 [192*192] | bias frags [6*4*64*16]
#define WQ16_OFF 0
#define WP16_OFF 110592
#define BIAS_OFF 147456
#define WS_HALFS (147456 + 24576)
#define WS_BYTES (WS_HALFS * 2)

typedef _Float16 f16x8 __attribute__((ext_vector_type(8)));
typedef _Float16 f16x4 __attribute__((ext_vector_type(4)));
typedef float f32x4 __attribute__((ext_vector_type(4)));

__device__ __forceinline__ f16x8 ld8(const _Float16* p) {
  return *reinterpret_cast<const f16x8*>(p);
}

__device__ __forceinline__ f16x8 cvt8(const float* __restrict__ p) {
  float4 a = *reinterpret_cast<const float4*>(p);
  float4 c = *reinterpret_cast<const float4*>(p + 4);
  f16x8 r;
  r[0] = (_Float16)a.x; r[1] = (_Float16)a.y; r[2] = (_Float16)a.z; r[3] = (_Float16)a.w;
  r[4] = (_Float16)c.x; r[5] = (_Float16)c.y; r[6] = (_Float16)c.z; r[7] = (_Float16)c.w;
  return r;
}

// Prologue: fp16 weights + per-(head,row-tile) bias fragments (two f16x8 per lane).
__global__ void prep_ws(const float* __restrict__ wq, const float* __restrict__ wp,
                        const float* __restrict__ bt, _Float16* __restrict__ ws) {
  int i = blockIdx.x * 256 + threadIdx.x;
  if (i < 27648) {
    float4 v = reinterpret_cast<const float4*>(wq)[i];
    f16x4 h;
    h[0] = (_Float16)v.x; h[1] = (_Float16)v.y; h[2] = (_Float16)v.z; h[3] = (_Float16)v.w;
    *reinterpret_cast<f16x4*>(ws + WQ16_OFF + (size_t)i * 4) = h;
  } else if (i < 36864) {
    int j = i - 27648;
    float4 v = reinterpret_cast<const float4*>(wp)[j];
    f16x4 h;
    h[0] = (_Float16)v.x; h[1] = (_Float16)v.y; h[2] = (_Float16)v.z; h[3] = (_Float16)v.w;
    *reinterpret_cast<f16x4*>(ws + WP16_OFF + (size_t)j * 4) = h;
  } else if (i < 61440) {
    int j = i - 36864;            // ((h*4+it)*64 + lane)*16 + (jt*4+r)
    int hit = j >> 10;
    int l = (j >> 4) & 63;
    int s = j & 15;
    int h = hit >> 2, it = hit & 3;
    int ii = it * 16 + (l & 15);
    int jj = (s >> 2) * 16 + (l >> 4) * 4 + (s & 3);
    int rel = ((ii >> 3) - (jj >> 3) + 7) * 15 + ((ii & 7) - (jj & 7) + 7);
    ws[BIAS_OFF + j] = (_Float16)bt[rel * NH + h];
  }
}

// Fused window attention: 1 block = 1 window, 12 waves, 48 KB LDS -> 2 blocks/CU.
// Round 8: XOR token-swizzle with HAND-FOLDED addressing (all panel XOR consts
// reduce to sA0 = l15^lg or sA1 = sA0^4 -> ~2 extra VGPRs, vs round 7's ~12
// which spilled). QKV restructured to 2 rowtiles x 6 coltiles per wave in two
// passes (A: q,q,k / B: k,v,v) -> A-fragment LDS reads halve; proj 2x2.
// Overlay chains: R1: x -> v^T -> O      R2: k -> q -> P slices
template <bool WS>
__global__ __launch_bounds__(THREADS, 6) void winattn(
    const float* __restrict__ x, const float* __restrict__ w_qkv,
    const float* __restrict__ b_qkv, const float* __restrict__ w_proj,
    const float* __restrict__ b_proj, const float* __restrict__ bias_table,
    const _Float16* __restrict__ ws, float* __restrict__ out) {
  __shared__ __align__(16) _Float16 R1[12288];  // x -> v^T -> O
  __shared__ __align__(16) _Float16 R2[12288];  // k -> q -> P

  const int tid = threadIdx.x;
  const int w   = tid >> 6;   // 0..11
  const int l   = tid & 63;
  const int l15 = l & 15;
  const int lg  = l >> 4;
  const int b   = blockIdx.x;
  // attention mapping
  const int h   = w >> 1;     // head
  const int wh  = w & 1;      // row half
  // QKV / proj mapping
  const int rh  = w & 1;      // token half (rows rh*32..rh*32+31)
  const int cg  = w >> 1;     // column group (0..5)
  // swizzle lane constants (all panel XORs fold to one of these)
  const int sA0 = l15 ^ lg;
  const int sA1 = sA0 ^ 4;
  const f32x4 vzero = {0.f, 0.f, 0.f, 0.f};

  // ---------------- stage x (fp32 -> fp16 swizzled panels) ----------------
  const float* xg = x + (size_t)b * (TOK * CDIM);
#pragma unroll
  for (int kk = 0; kk < 2; ++kk) {
    int q = tid + kk * 768;
    int n = q / 24;              // token
    int p = q - n * 24;          // c-panel
    const float* src = xg + q * 8;
    float4 v0 = *reinterpret_cast<const float4*>(src);
    float4 v1 = *reinterpret_cast<const float4*>(src + 4);
    f16x8 h8;
    h8[0] = (_Float16)v0.x; h8[1] = (_Float16)v0.y;
    h8[2] = (_Float16)v0.z; h8[3] = (_Float16)v0.w;
    h8[4] = (_Float16)v1.x; h8[5] = (_Float16)v1.y;
    h8[6] = (_Float16)v1.z; h8[7] = (_Float16)v1.w;
    *reinterpret_cast<f16x8*>(&R1[(p * TOK + (n ^ (p & 7))) * 8]) = h8;
  }
  __syncthreads();  // b0

  // QKV shared lane geometry: all 6 tiles share hd/dp (parity of cg+6j == parity of cg)
  const int hd  = (cg & 1) * 16 + l15;   // dim within head
  const int dp  = hd >> 3;               // d-panel 0..3
  const int h0  = cg >> 1;               // head for even j tiles
  const int h1  = h0 + 3;                // head for odd j tiles
  const int wr0 = cg * 16 + l15;         // ws row base (dl for even j)

  // ------- QKV pass A: tiles j=0(q,h0) j=1(q,h1) j=2(k,h0) -------
  f32x4 aq0[2], aq1[2], akk[2];
#pragma unroll
  for (int mt = 0; mt < 2; ++mt) { aq0[mt] = vzero; aq1[mt] = vzero; akk[mt] = vzero; }
#pragma unroll
  for (int ks = 0; ks < 6; ++ks) {
    const int sx = (ks & 1) ? sA1 : sA0;
    f16x8 a[2];
#pragma unroll
    for (int mt = 0; mt < 2; ++mt)
      a[mt] = ld8(&R1[((ks * 4 + lg) * TOK + rh * 32 + mt * 16 + sx) * 8]);
    f16x8 b0, b1, b2;
    if constexpr (WS) {
      b0 = ld8(ws + WQ16_OFF + (size_t)wr0 * CDIM + ks * 32 + lg * 8);
      b1 = ld8(ws + WQ16_OFF + (size_t)(wr0 + 96) * CDIM + ks * 32 + lg * 8);
      b2 = ld8(ws + WQ16_OFF + (size_t)(wr0 + CDIM) * CDIM + ks * 32 + lg * 8);
    } else {
      b0 = cvt8(w_qkv + (size_t)wr0 * CDIM + ks * 32 + lg * 8);
      b1 = cvt8(w_qkv + (size_t)(wr0 + 96) * CDIM + ks * 32 + lg * 8);
      b2 = cvt8(w_qkv + (size_t)(wr0 + CDIM) * CDIM + ks * 32 + lg * 8);
    }
    __builtin_amdgcn_s_setprio(1);
#pragma unroll
    for (int mt = 0; mt < 2; ++mt) {
      aq0[mt] = __builtin_amdgcn_mfma_f32_16x16x32_f16(a[mt], b0, aq0[mt], 0, 0, 0);
      aq1[mt] = __builtin_amdgcn_mfma_f32_16x16x32_f16(a[mt], b1, aq1[mt], 0, 0, 0);
      akk[mt] = __builtin_amdgcn_mfma_f32_16x16x32_f16(a[mt], b2, akk[mt], 0, 0, 0);
    }
    __builtin_amdgcn_s_setprio(0);
  }
  // k tile (h0) -> R2; slot = token ^ dp (address-XOR, value index static)
  {
    float bk = b_qkv[CDIM + wr0];
#pragma unroll
    for (int mt = 0; mt < 2; ++mt) {
      int base = h0 * 2048 + (dp * TOK + rh * 32 + mt * 16 + lg * 4) * 8 + (hd & 7);
#pragma unroll
      for (int r = 0; r < 4; ++r)
        R2[base + (r ^ dp) * 8] = (_Float16)(akk[mt][r] + bk);
    }
  }

  // ------- QKV pass B: tiles j=3(k,h1) j=4(v,h0) j=5(v,h1) -------
  f32x4 ak3[2], av4[2], av5[2];
#pragma unroll
  for (int mt = 0; mt < 2; ++mt) { ak3[mt] = vzero; av4[mt] = vzero; av5[mt] = vzero; }
#pragma unroll
  for (int ks = 0; ks < 6; ++ks) {
    const int sx = (ks & 1) ? sA1 : sA0;
    f16x8 a[2];
#pragma unroll
    for (int mt = 0; mt < 2; ++mt)
      a[mt] = ld8(&R1[((ks * 4 + lg) * TOK + rh * 32 + mt * 16 + sx) * 8]);
    f16x8 b3, b4, b5;
    if constexpr (WS) {
      b3 = ld8(ws + WQ16_OFF + (size_t)(wr0 + CDIM + 96) * CDIM + ks * 32 + lg * 8);
      b4 = ld8(ws + WQ16_OFF + (size_t)(wr0 + 2 * CDIM) * CDIM + ks * 32 + lg * 8);
      b5 = ld8(ws + WQ16_OFF + (size_t)(wr0 + 2 * CDIM + 96) * CDIM + ks * 32 + lg * 8);
    } else {
      b3 = cvt8(w_qkv + (size_t)(wr0 + CDIM + 96) * CDIM + ks * 32 + lg * 8);
      b4 = cvt8(w_qkv + (size_t)(wr0 + 2 * CDIM) * CDIM + ks * 32 + lg * 8);
      b5 = cvt8(w_qkv + (size_t)(wr0 + 2 * CDIM + 96) * CDIM + ks * 32 + lg * 8);
    }
    __builtin_amdgcn_s_setprio(1);
#pragma unroll
    for (int mt = 0; mt < 2; ++mt) {
      ak3[mt] = __builtin_amdgcn_mfma_f32_16x16x32_f16(a[mt], b3, ak3[mt], 0, 0, 0);
      av4[mt] = __builtin_amdgcn_mfma_f32_16x16x32_f16(a[mt], b4, av4[mt], 0, 0, 0);
      av5[mt] = __builtin_amdgcn_mfma_f32_16x16x32_f16(a[mt], b5, av5[mt], 0, 0, 0);
    }
    __builtin_amdgcn_s_setprio(0);
  }
  // k tile (h1) -> R2
  {
    float bk = b_qkv[CDIM + wr0 + 96];
#pragma unroll
    for (int mt = 0; mt < 2; ++mt) {
      int base = h1 * 2048 + (dp * TOK + rh * 32 + mt * 16 + lg * 4) * 8 + (hd & 7);
#pragma unroll
      for (int r = 0; r < 4; ++r)
        R2[base + (r ^ dp) * 8] = (_Float16)(ak3[mt][r] + bk);
    }
  }
  __syncthreads();  // b1: x dead (R1 free), k visible

  // hoist kf (attention head h); v^T -> R1 over x (av4/av5 die), packed f16x4
  f16x8 kf[4];
#pragma unroll
  for (int jt = 0; jt < 4; ++jt)
    kf[jt] = ld8(&R2[h * 2048 + (lg * TOK + jt * 16 + sA0) * 8]);
  {
    float bv0 = b_qkv[2 * CDIM + wr0];
    float bv1 = b_qkv[2 * CDIM + wr0 + 96];
#pragma unroll
    for (int mt = 0; mt < 2; ++mt) {
      int vp = rh * 4 + mt * 2 + (lg >> 1);  // token-panel 0..7
      int slot = (cg & 1) * 16 + (l15 ^ vp); // d-row swizzled
      f16x4 p0, p1;
#pragma unroll
      for (int r = 0; r < 4; ++r) {
        p0[r] = (_Float16)(av4[mt][r] + bv0);
        p1[r] = (_Float16)(av5[mt][r] + bv1);
      }
      *reinterpret_cast<f16x4*>(&R1[h0 * 2048 + (vp * HD + slot) * 8 + (lg & 1) * 4]) = p0;
      *reinterpret_cast<f16x4*>(&R1[h1 * 2048 + (vp * HD + slot) * 8 + (lg & 1) * 4]) = p1;
    }
  }
  __syncthreads();  // b2: v^T visible, k dead (R2 free for q)

  // hoist vf; q -> R2 over k (aq0/aq1 die)
  f16x8 vf[4];
#pragma unroll
  for (int z = 0; z < 4; ++z) {  // z = ks2*2+nt
    int ks2 = z >> 1, nt = z & 1;
    int sx = ks2 ? sA1 : sA0;
    vf[z] = ld8(&R1[h * 2048 + ((ks2 * 4 + lg) * HD + nt * 16 + sx) * 8]);
  }
  {
    float bq0 = b_qkv[wr0];
    float bq1 = b_qkv[wr0 + 96];
#pragma unroll
    for (int mt = 0; mt < 2; ++mt) {
      int base0 = h0 * 2048 + (dp * TOK + rh * 32 + mt * 16 + lg * 4) * 8 + (hd & 7);
      int base1 = h1 * 2048 + (dp * TOK + rh * 32 + mt * 16 + lg * 4) * 8 + (hd & 7);
#pragma unroll
      for (int r = 0; r < 4; ++r) {
        R2[base0 + (r ^ dp) * 8] = (_Float16)((aq0[mt][r] + bq0) * QSCALE);
        R2[base1 + (r ^ dp) * 8] = (_Float16)((aq1[mt][r] + bq1) * QSCALE);
      }
    }
  }
  __syncthreads();  // b3: q visible, v^T dead (R1 free for O)

  // hoist qf (attention rows)
  f16x8 qf[2];
#pragma unroll
  for (int ii = 0; ii < 2; ++ii)
    qf[ii] = ld8(&R2[h * 2048 + (lg * TOK + (wh * 2 + ii) * 16 + sA0) * 8]);
  __syncthreads();  // b4: q dead -> R2 free for P slices

  // ---------------- attention: 2 row-tiles per wave ----------------
  {
    _Float16* pbase = &R2[w * 1024];  // 2 KB P slice per wave
#pragma unroll
    for (int ii = 0; ii < 2; ++ii) {
      const int it = wh * 2 + ii;
      f32x4 st[4];
      __builtin_amdgcn_s_setprio(1);
#pragma unroll
      for (int jt = 0; jt < 4; ++jt)
        st[jt] = __builtin_amdgcn_mfma_f32_16x16x32_f16(kf[jt], qf[ii], vzero, 0, 0, 0);
      __builtin_amdgcn_s_setprio(0);
      // bias
      if constexpr (WS) {
        const _Float16* bw = ws + BIAS_OFF + ((h * 4 + it) * 64 + l) * 16;
        f16x8 b0 = ld8(bw), b1 = ld8(bw + 8);
#pragma unroll
        for (int jt = 0; jt < 4; ++jt)
#pragma unroll
          for (int r = 0; r < 4; ++r)
            st[jt][r] += (float)((jt < 2) ? b0[jt * 4 + r] : b1[(jt - 2) * 4 + r]);
      } else {
        int i = it * 16 + l15, yi = i >> 3, xi = i & 7;
#pragma unroll
        for (int jt = 0; jt < 4; ++jt)
#pragma unroll
          for (int r = 0; r < 4; ++r) {
            int j = jt * 16 + lg * 4 + r, yj = j >> 3, xj = j & 7;
            st[jt][r] += bias_table[(((yi - yj + 7) * 15 + (xi - xj + 7)) * NH + h)];
          }
      }
      // softmax
      float m = st[0][0];
#pragma unroll
      for (int jt = 0; jt < 4; ++jt)
#pragma unroll
        for (int r = 0; r < 4; ++r) m = fmaxf(m, st[jt][r]);
      m = fmaxf(m, __shfl_xor(m, 16, 64));
      m = fmaxf(m, __shfl_xor(m, 32, 64));
      float sum = 0.f;
#pragma unroll
      for (int jt = 0; jt < 4; ++jt)
#pragma unroll
        for (int r = 0; r < 4; ++r) { st[jt][r] = __expf(st[jt][r] - m); sum += st[jt][r]; }
      sum += __shfl_xor(sum, 16, 64);
      sum += __shfl_xor(sum, 32, 64);
      float inv = 1.f / sum;
      // P slice write (packed f16x4), layout [j>>3][i16][j&7]
#pragma unroll
      for (int jt = 0; jt < 4; ++jt) {
        f16x4 pk;
#pragma unroll
        for (int r = 0; r < 4; ++r) pk[r] = (_Float16)(st[jt][r] * inv);
        *reinterpret_cast<f16x4*>(
            &pbase[((jt * 2 + (lg >> 1)) * 16 + l15) * 8 + (lg & 1) * 4]) = pk;
      }
      // PV
      f32x4 o[2] = {vzero, vzero};
#pragma unroll
      for (int ks = 0; ks < 2; ++ks) {
        f16x8 pf = ld8(&pbase[((ks * 4 + lg) * 16 + l15) * 8]);
        __builtin_amdgcn_s_setprio(1);
#pragma unroll
        for (int nt = 0; nt < 2; ++nt)
          o[nt] = __builtin_amdgcn_mfma_f32_16x16x32_f16(pf, vf[ks * 2 + nt], o[nt], 0, 0, 0);
        __builtin_amdgcn_s_setprio(0);
      }
      // O -> R1 swizzled flat panels (address-XOR folded, value index static)
#pragma unroll
      for (int nt = 0; nt < 2; ++nt) {
        int c = h * HD + nt * 16 + l15;
        int op = c >> 3;
        int c7 = op & 7;
        int lgx = lg ^ (c7 >> 2);
        int c73 = c7 & 3;
        int base = (op * TOK + it * 16 + lgx * 4) * 8 + (c & 7);
#pragma unroll
        for (int r = 0; r < 4; ++r)
          R1[base + (r ^ c73) * 8] = (_Float16)o[nt][r];
      }
    }
  }
  __syncthreads();  // b5: O visible

  // ------- projection: wave -> 2 rowtiles x 2 e-tiles {cg, cg+6} -------
  {
    const int e0 = cg * 16 + l15;
    const int e1 = e0 + 96;
    f32x4 pa0[2], pa1[2];
#pragma unroll
    for (int mt = 0; mt < 2; ++mt) { pa0[mt] = vzero; pa1[mt] = vzero; }
#pragma unroll
    for (int ks = 0; ks < 6; ++ks) {
      const int sx = (ks & 1) ? sA1 : sA0;
      f16x8 a[2];
#pragma unroll
      for (int mt = 0; mt < 2; ++mt)
        a[mt] = ld8(&R1[((ks * 4 + lg) * TOK + rh * 32 + mt * 16 + sx) * 8]);
      f16x8 b0, b1;
      if constexpr (WS) {
        b0 = ld8(ws + WP16_OFF + (size_t)e0 * CDIM + ks * 32 + lg * 8);
        b1 = ld8(ws + WP16_OFF + (size_t)e1 * CDIM + ks * 32 + lg * 8);
      } else {
        b0 = cvt8(w_proj + (size_t)e0 * CDIM + ks * 32 + lg * 8);
        b1 = cvt8(w_proj + (size_t)e1 * CDIM + ks * 32 + lg * 8);
      }
      __builtin_amdgcn_s_setprio(1);
#pragma unroll
      for (int mt = 0; mt < 2; ++mt) {
        pa0[mt] = __builtin_amdgcn_mfma_f32_16x16x32_f16(a[mt], b0, pa0[mt], 0, 0, 0);
        pa1[mt] = __builtin_amdgcn_mfma_f32_16x16x32_f16(a[mt], b1, pa1[mt], 0, 0, 0);
      }
      __builtin_amdgcn_s_setprio(0);
    }
    float bp0 = b_proj[e0], bp1 = b_proj[e1];
#pragma unroll
    for (int mt = 0; mt < 2; ++mt) {
#pragma unroll
      for (int r = 0; r < 4; ++r) {
        int n = rh * 32 + mt * 16 + lg * 4 + r;
        out[((size_t)b * TOK + n) * CDIM + e0] = pa0[mt][r] + bp0;
        out[((size_t)b * TOK + n) * CDIM + e1] = pa1[mt][r] + bp1;
      }
    }
  }
}

extern "C" void kernel_launch(void* const* d_in, const int* in_sizes, int n_in,
                              void* d_out, int out_size, void* d_ws, size_t ws_size,
                              hipStream_t stream) {
  const float* x          = (const float*)d_in[0];
  const float* w_qkv      = (const float*)d_in[1];
  const float* b_qkv      = (const float*)d_in[2];
  const float* w_proj     = (const float*)d_in[3];
  const float* b_proj     = (const float*)d_in[4];
  const float* bias_table = (const float*)d_in[5];
  float* out = (float*)d_out;
  int B = in_sizes[0] / (TOK * CDIM);

  if (ws_size >= (size_t)WS_BYTES) {
    _Float16* ws = (_Float16*)d_ws;
    hipLaunchKernelGGL(prep_ws, dim3(240), dim3(256), 0, stream,
                       w_qkv, w_proj, bias_table, ws);
    hipLaunchKernelGGL(winattn<true>, dim3(B), dim3(THREADS), 0, stream,
                       x, w_qkv, b_qkv, w_proj, b_proj, bias_table, ws, out);
  } else {
    hipLaunchKernelGGL(winattn<false>, dim3(B), dim3(THREADS), 0, stream,
                       x, w_qkv, b_qkv, w_proj, b_proj, bias_table,
                       (const _Float16*)nullptr, out);
  }
}

// Round 9
// 243.523 us; speedup vs baseline: 1.6202x; 1.5829x over previous
//
#include <hip/hip_runtime.h>

#define TOK 64
#define CDIM 192
#define NH 6
#define HD 32
#define THREADS 384
#define QSCALE 0.17677669529663687f  // 32^-0.5

// workspace layout (halfs): w_qkv16 [576*192] | w_proj16 [192*192] | bias frags [6*4*64*16]
#define WQ16_OFF 0
#define WP16_OFF 110592
#define BIAS_OFF 147456
#define WS_HALFS (147456 + 24576)
#define WS_BYTES (WS_HALFS * 2)

typedef _Float16 f16x8 __attribute__((ext_vector_type(8)));
typedef _Float16 f16x4 __attribute__((ext_vector_type(4)));
typedef float f32x4 __attribute__((ext_vector_type(4)));

__device__ __forceinline__ f16x8 ld8(const _Float16* p) {
  return *reinterpret_cast<const f16x8*>(p);
}

__device__ __forceinline__ f16x8 cvt8(const float* __restrict__ p) {
  float4 a = *reinterpret_cast<const float4*>(p);
  float4 c = *reinterpret_cast<const float4*>(p + 4);
  f16x8 r;
  r[0] = (_Float16)a.x; r[1] = (_Float16)a.y; r[2] = (_Float16)a.z; r[3] = (_Float16)a.w;
  r[4] = (_Float16)c.x; r[5] = (_Float16)c.y; r[6] = (_Float16)c.z; r[7] = (_Float16)c.w;
  return r;
}

__device__ __forceinline__ f16x4 pack4(float a, float b, float c, float d) {
  f16x4 r;
  r[0] = (_Float16)a; r[1] = (_Float16)b; r[2] = (_Float16)c; r[3] = (_Float16)d;
  return r;
}

// Prologue: fp16 weights + per-(head,row-tile) bias fragments (two f16x8 per lane).
__global__ void prep_ws(const float* __restrict__ wq, const float* __restrict__ wp,
                        const float* __restrict__ bt, _Float16* __restrict__ ws) {
  int i = blockIdx.x * 256 + threadIdx.x;
  if (i < 27648) {
    float4 v = reinterpret_cast<const float4*>(wq)[i];
    f16x4 h;
    h[0] = (_Float16)v.x; h[1] = (_Float16)v.y; h[2] = (_Float16)v.z; h[3] = (_Float16)v.w;
    *reinterpret_cast<f16x4*>(ws + WQ16_OFF + (size_t)i * 4) = h;
  } else if (i < 36864) {
    int j = i - 27648;
    float4 v = reinterpret_cast<const float4*>(wp)[j];
    f16x4 h;
    h[0] = (_Float16)v.x; h[1] = (_Float16)v.y; h[2] = (_Float16)v.z; h[3] = (_Float16)v.w;
    *reinterpret_cast<f16x4*>(ws + WP16_OFF + (size_t)j * 4) = h;
  } else if (i < 61440) {
    int j = i - 36864;            // ((h*4+it)*64 + lane)*16 + (jt*4+r)
    int hit = j >> 10;
    int l = (j >> 4) & 63;
    int s = j & 15;
    int h = hit >> 2, it = hit & 3;
    int ii = it * 16 + (l & 15);
    int jj = (s >> 2) * 16 + (l >> 4) * 4 + (s & 3);
    int rel = ((ii >> 3) - (jj >> 3) + 7) * 15 + ((ii & 7) - (jj & 7) + 7);
    ws[BIAS_OFF + j] = (_Float16)bt[rel * NH + h];
  }
}

// Transpose-free fused window attention. 1 block = 1 window, 6 waves (1 head
// each), 24 KB LDS, 3 barriers, 102-reg budget (384,5) -> 3 blocks/CU.
// Key identity: for mfma_f32_16x16x16_f16 the A/B k-slice per lane
// ((l>>4)*4..+3) equals the D-row indexing ((l>>4)*4+reg), so:
//   q,k: SWAPPED GEMM (A=W rows=d, B=x cols=tokens) -> packed acc IS the
//        QK^T operand fragment (q:B, k:A) per 16-d step. No LDS, no shuffle.
//   S:   lane = q-token, rows = kv -> in-lane softmax (+2 shfl_xor).
//   P:   packed in-lane IS the PV A-frag per 16-kv step.
//   v:   STANDARD GEMM (lane = d, rows = kv) -> packed acc IS the PV B-frag.
// Only O->proj goes through LDS (overlays x panels).
// x/O panel layout: [panel p][token n ^ (p&7)][k&7] -> conflict-light staging,
// all fragment reads are contiguous ds_read_b128 (fold: sA0 = l15^lg, sA1 = sA0^4).
template <bool WS>
__global__ __launch_bounds__(THREADS, 5) void winattn(
    const float* __restrict__ x, const float* __restrict__ w_qkv,
    const float* __restrict__ b_qkv, const float* __restrict__ w_proj,
    const float* __restrict__ b_proj, const float* __restrict__ bias_table,
    const _Float16* __restrict__ ws, float* __restrict__ out) {
  __shared__ __align__(16) _Float16 R1[12288];  // x panels -> O panels

  const int tid = threadIdx.x;
  const int h   = tid >> 6;   // wave == head (0..5)
  const int l   = tid & 63;
  const int l15 = l & 15;
  const int lg  = l >> 4;
  const int b   = blockIdx.x;
  const int sA0 = l15 ^ lg;
  const int sA1 = sA0 ^ 4;
  const f32x4 vzero = {0.f, 0.f, 0.f, 0.f};

  // ---------------- stage x (fp32 -> fp16 swizzled panels) ----------------
  const float* xg = x + (size_t)b * (TOK * CDIM);
#pragma unroll
  for (int kk = 0; kk < 4; ++kk) {
    int q = tid + kk * THREADS;
    int n = q / 24;              // token
    int p = q - n * 24;          // c-panel
    const float* src = xg + q * 8;
    float4 v0 = *reinterpret_cast<const float4*>(src);
    float4 v1 = *reinterpret_cast<const float4*>(src + 4);
    f16x8 h8;
    h8[0] = (_Float16)v0.x; h8[1] = (_Float16)v0.y;
    h8[2] = (_Float16)v0.z; h8[3] = (_Float16)v0.w;
    h8[4] = (_Float16)v1.x; h8[5] = (_Float16)v1.y;
    h8[6] = (_Float16)v1.z; h8[7] = (_Float16)v1.w;
    *reinterpret_cast<f16x8*>(&R1[(p * TOK + (n ^ (p & 7))) * 8]) = h8;
  }
  __syncthreads();  // b0

  // ------- q GEMM, swapped: D lane = token, rows = d -------
  f32x4 aq[2][4];
#pragma unroll
  for (int mt = 0; mt < 2; ++mt)
#pragma unroll
    for (int nt = 0; nt < 4; ++nt) aq[mt][nt] = vzero;
#pragma unroll
  for (int ks = 0; ks < 6; ++ks) {
    const int sx = (ks & 1) ? sA1 : sA0;
    f16x8 bx[4];
#pragma unroll
    for (int nt = 0; nt < 4; ++nt)
      bx[nt] = ld8(&R1[((ks * 4 + lg) * TOK + nt * 16 + sx) * 8]);
    f16x8 aw[2];
#pragma unroll
    for (int mt = 0; mt < 2; ++mt) {
      int row = h * HD + mt * 16 + l15;
      if constexpr (WS) aw[mt] = ld8(ws + WQ16_OFF + (size_t)row * CDIM + ks * 32 + lg * 8);
      else              aw[mt] = cvt8(w_qkv + (size_t)row * CDIM + ks * 32 + lg * 8);
    }
    __builtin_amdgcn_s_setprio(1);
#pragma unroll
    for (int mt = 0; mt < 2; ++mt)
#pragma unroll
      for (int nt = 0; nt < 4; ++nt)
        aq[mt][nt] = __builtin_amdgcn_mfma_f32_16x16x32_f16(aw[mt], bx[nt], aq[mt][nt], 0, 0, 0);
    __builtin_amdgcn_s_setprio(0);
  }
  f16x4 qp[2][4];  // packed q: [d-step][token-tile], lane = token, elems = d lg*4+r
#pragma unroll
  for (int mt = 0; mt < 2; ++mt) {
    float4 bq = *reinterpret_cast<const float4*>(b_qkv + h * HD + mt * 16 + lg * 4);
#pragma unroll
    for (int nt = 0; nt < 4; ++nt)
      qp[mt][nt] = pack4((aq[mt][nt][0] + bq.x) * QSCALE, (aq[mt][nt][1] + bq.y) * QSCALE,
                         (aq[mt][nt][2] + bq.z) * QSCALE, (aq[mt][nt][3] + bq.w) * QSCALE);
  }

  // ------- k GEMM, swapped -------
  f32x4 ak[2][4];
#pragma unroll
  for (int mt = 0; mt < 2; ++mt)
#pragma unroll
    for (int nt = 0; nt < 4; ++nt) ak[mt][nt] = vzero;
#pragma unroll
  for (int ks = 0; ks < 6; ++ks) {
    const int sx = (ks & 1) ? sA1 : sA0;
    f16x8 bx[4];
#pragma unroll
    for (int nt = 0; nt < 4; ++nt)
      bx[nt] = ld8(&R1[((ks * 4 + lg) * TOK + nt * 16 + sx) * 8]);
    f16x8 aw[2];
#pragma unroll
    for (int mt = 0; mt < 2; ++mt) {
      int row = CDIM + h * HD + mt * 16 + l15;
      if constexpr (WS) aw[mt] = ld8(ws + WQ16_OFF + (size_t)row * CDIM + ks * 32 + lg * 8);
      else              aw[mt] = cvt8(w_qkv + (size_t)row * CDIM + ks * 32 + lg * 8);
    }
    __builtin_amdgcn_s_setprio(1);
#pragma unroll
    for (int mt = 0; mt < 2; ++mt)
#pragma unroll
      for (int nt = 0; nt < 4; ++nt)
        ak[mt][nt] = __builtin_amdgcn_mfma_f32_16x16x32_f16(aw[mt], bx[nt], ak[mt][nt], 0, 0, 0);
    __builtin_amdgcn_s_setprio(0);
  }
  f16x4 kp[2][4];  // packed k: [d-step][kv-tile]
#pragma unroll
  for (int mt = 0; mt < 2; ++mt) {
    float4 bk = *reinterpret_cast<const float4*>(b_qkv + CDIM + h * HD + mt * 16 + lg * 4);
#pragma unroll
    for (int nt = 0; nt < 4; ++nt)
      kp[mt][nt] = pack4(ak[mt][nt][0] + bk.x, ak[mt][nt][1] + bk.y,
                         ak[mt][nt][2] + bk.z, ak[mt][nt][3] + bk.w);
  }

  // ------- v GEMM, standard (lane = d, rows = kv), 2 ct passes -------
  f16x4 vp[4][2];  // packed v: [kv-step][d-tile], lane = d, elems = kv lg*4+r
#pragma unroll
  for (int ct = 0; ct < 2; ++ct) {
    f32x4 av[4];
#pragma unroll
    for (int mt = 0; mt < 4; ++mt) av[mt] = vzero;
    const int col = 2 * CDIM + h * HD + ct * 16 + l15;
#pragma unroll
    for (int ks = 0; ks < 6; ++ks) {
      const int sx = (ks & 1) ? sA1 : sA0;
      f16x8 a[4];
#pragma unroll
      for (int mt = 0; mt < 4; ++mt)
        a[mt] = ld8(&R1[((ks * 4 + lg) * TOK + mt * 16 + sx) * 8]);
      f16x8 bw;
      if constexpr (WS) bw = ld8(ws + WQ16_OFF + (size_t)col * CDIM + ks * 32 + lg * 8);
      else              bw = cvt8(w_qkv + (size_t)col * CDIM + ks * 32 + lg * 8);
      __builtin_amdgcn_s_setprio(1);
#pragma unroll
      for (int mt = 0; mt < 4; ++mt)
        av[mt] = __builtin_amdgcn_mfma_f32_16x16x32_f16(a[mt], bw, av[mt], 0, 0, 0);
      __builtin_amdgcn_s_setprio(0);
    }
    float bv = b_qkv[col];
#pragma unroll
    for (int s = 0; s < 4; ++s)
      vp[s][ct] = pack4(av[s][0] + bv, av[s][1] + bv, av[s][2] + bv, av[s][3] + bv);
  }
  __syncthreads();  // b1: all x reads done -> R1 free for O

  // ---------------- attention: 4 row-tiles, all in-register ----------------
#pragma unroll
  for (int it = 0; it < 4; ++it) {
    f32x4 st[4];  // S: lane = q-token (it*16+l15), rows = kv = jt*16+lg*4+r
    __builtin_amdgcn_s_setprio(1);
#pragma unroll
    for (int jt = 0; jt < 4; ++jt) {
      st[jt] = __builtin_amdgcn_mfma_f32_16x16x16f16(kp[0][jt], qp[0][it], vzero, 0, 0, 0);
      st[jt] = __builtin_amdgcn_mfma_f32_16x16x16f16(kp[1][jt], qp[1][it], st[jt], 0, 0, 0);
    }
    __builtin_amdgcn_s_setprio(0);
    // bias
    if constexpr (WS) {
      const _Float16* bw = ws + BIAS_OFF + ((h * 4 + it) * 64 + l) * 16;
      f16x8 b0 = ld8(bw), b1 = ld8(bw + 8);
#pragma unroll
      for (int jt = 0; jt < 4; ++jt)
#pragma unroll
        for (int r = 0; r < 4; ++r)
          st[jt][r] += (float)((jt < 2) ? b0[jt * 4 + r] : b1[(jt - 2) * 4 + r]);
    } else {
      int i = it * 16 + l15, yi = i >> 3, xi = i & 7;
#pragma unroll
      for (int jt = 0; jt < 4; ++jt)
#pragma unroll
        for (int r = 0; r < 4; ++r) {
          int j = jt * 16 + lg * 4 + r, yj = j >> 3, xj = j & 7;
          st[jt][r] += bias_table[(((yi - yj + 7) * 15 + (xi - xj + 7)) * NH + h)];
        }
    }
    // softmax over kv: 16 in-lane + cross-lg (xor 16, 32)
    float m = st[0][0];
#pragma unroll
    for (int jt = 0; jt < 4; ++jt)
#pragma unroll
      for (int r = 0; r < 4; ++r) m = fmaxf(m, st[jt][r]);
    m = fmaxf(m, __shfl_xor(m, 16, 64));
    m = fmaxf(m, __shfl_xor(m, 32, 64));
    float sum = 0.f;
#pragma unroll
    for (int jt = 0; jt < 4; ++jt)
#pragma unroll
      for (int r = 0; r < 4; ++r) { st[jt][r] = __expf(st[jt][r] - m); sum += st[jt][r]; }
    sum += __shfl_xor(sum, 16, 64);
    sum += __shfl_xor(sum, 32, 64);
    float inv = 1.f / sum;
    // P pack (in-lane) + PV
    f32x4 o[2] = {vzero, vzero};
#pragma unroll
    for (int s = 0; s < 4; ++s) {
      f16x4 pp = pack4(st[s][0] * inv, st[s][1] * inv, st[s][2] * inv, st[s][3] * inv);
      __builtin_amdgcn_s_setprio(1);
      o[0] = __builtin_amdgcn_mfma_f32_16x16x16f16(pp, vp[s][0], o[0], 0, 0, 0);
      o[1] = __builtin_amdgcn_mfma_f32_16x16x16f16(pp, vp[s][1], o[1], 0, 0, 0);
      __builtin_amdgcn_s_setprio(0);
    }
    // O -> R1 swizzled panels (lane = d col, rows = q-token it*16+lg*4+r)
#pragma unroll
    for (int ct = 0; ct < 2; ++ct) {
      int c = h * HD + ct * 16 + l15;
      int op = c >> 3, s7 = op & 7;
      int lgx = lg ^ (s7 >> 2);
      int base = (op * TOK + it * 16 + lgx * 4) * 8 + (c & 7);
#pragma unroll
      for (int r = 0; r < 4; ++r)
        R1[base + (r ^ (s7 & 3)) * 8] = (_Float16)o[ct][r];
    }
  }
  __syncthreads();  // b2: O visible

  // ------- projection (64x192, K=192); wave h -> e-tiles {h, h+6} -------
  {
    const int e0 = h * 16 + l15;
    const int e1 = e0 + 96;
    f32x4 pa0[4], pa1[4];
#pragma unroll
    for (int mt = 0; mt < 4; ++mt) { pa0[mt] = vzero; pa1[mt] = vzero; }
#pragma unroll
    for (int ks = 0; ks < 6; ++ks) {
      const int sx = (ks & 1) ? sA1 : sA0;
      f16x8 a[4];
#pragma unroll
      for (int mt = 0; mt < 4; ++mt)
        a[mt] = ld8(&R1[((ks * 4 + lg) * TOK + mt * 16 + sx) * 8]);
      f16x8 w0, w1;
      if constexpr (WS) {
        w0 = ld8(ws + WP16_OFF + (size_t)e0 * CDIM + ks * 32 + lg * 8);
        w1 = ld8(ws + WP16_OFF + (size_t)e1 * CDIM + ks * 32 + lg * 8);
      } else {
        w0 = cvt8(w_proj + (size_t)e0 * CDIM + ks * 32 + lg * 8);
        w1 = cvt8(w_proj + (size_t)e1 * CDIM + ks * 32 + lg * 8);
      }
      __builtin_amdgcn_s_setprio(1);
#pragma unroll
      for (int mt = 0; mt < 4; ++mt) {
        pa0[mt] = __builtin_amdgcn_mfma_f32_16x16x32_f16(a[mt], w0, pa0[mt], 0, 0, 0);
        pa1[mt] = __builtin_amdgcn_mfma_f32_16x16x32_f16(a[mt], w1, pa1[mt], 0, 0, 0);
      }
      __builtin_amdgcn_s_setprio(0);
    }
    float bp0 = b_proj[e0], bp1 = b_proj[e1];
#pragma unroll
    for (int mt = 0; mt < 4; ++mt) {
#pragma unroll
      for (int r = 0; r < 4; ++r) {
        int n = mt * 16 + lg * 4 + r;
        out[((size_t)b * TOK + n) * CDIM + e0] = pa0[mt][r] + bp0;
        out[((size_t)b * TOK + n) * CDIM + e1] = pa1[mt][r] + bp1;
      }
    }
  }
}

extern "C" void kernel_launch(void* const* d_in, const int* in_sizes, int n_in,
                              void* d_out, int out_size, void* d_ws, size_t ws_size,
                              hipStream_t stream) {
  const float* x          = (const float*)d_in[0];
  const float* w_qkv      = (const float*)d_in[1];
  const float* b_qkv      = (const float*)d_in[2];
  const float* w_proj     = (const float*)d_in[3];
  const float* b_proj     = (const float*)d_in[4];
  const float* bias_table = (const float*)d_in[5];
  float* out = (float*)d_out;
  int B = in_sizes[0] / (TOK * CDIM);

  if (ws_size >= (size_t)WS_BYTES) {
    _Float16* ws = (_Float16*)d_ws;
    hipLaunchKernelGGL(prep_ws, dim3(240), dim3(256), 0, stream,
                       w_qkv, w_proj, bias_table, ws);
    hipLaunchKernelGGL(winattn<true>, dim3(B), dim3(THREADS), 0, stream,
                       x, w_qkv, b_qkv, w_proj, b_proj, bias_table, ws, out);
  } else {
    hipLaunchKernelGGL(winattn<false>, dim3(B), dim3(THREADS), 0, stream,
                       x, w_qkv, b_qkv, w_proj, b_proj, bias_table,
                       (const _Float16*)nullptr, out);
  }
}